// Round 15
// baseline (351.712 us; speedup 1.0000x reference)
//
#include <hip/hip_runtime.h>

// ---------------- problem constants ----------------
#define N_ANCH 221184      // H*W*A = 128*192*9
#define HW     24576       // H*W
#define Wd     192
#define AA     9
#define TOPN   6000
#define POSTN  300
#define CAND_CAP 8192
#define NWORDS 94          // ceil(6016/64) words of suppression bits
#define NCHUNK 47          // 6016 / 128
#define NBUCK  32768       // 15-bit select buckets
#define BSHIFT 17          // key >> BSHIFT = bucket

typedef unsigned long long u64;

// anchor widths/heights (== ws2/hs2 of the reference, exact small ints)
__device__ const float c_aw[9] = {184.f,368.f,736.f,128.f,256.f,512.f, 88.f,176.f,352.f};
__device__ const float c_ah[9] = { 96.f,192.f,384.f,128.f,256.f,512.f,176.f,352.f,704.f};

// bucket -> storage index rotation (r9 lesson: scatter hot value-adjacent
// buckets across cache lines/L2 channels).
__device__ __forceinline__ unsigned int rot15(unsigned int b) {
    return ((b << 7) | (b >> 8)) & 0x7FFFu;
}

// shared box decode — used by decode_kernel AND rank_scatter so the FP
// sequence (and thus every bit of the box) is identical in both places.
__device__ __forceinline__ float4 decode_box(int a, int cell,
                                             const float* __restrict__ deltas,
                                             float info0, float info1, float info2,
                                             bool* valid) {
    int h = cell / Wd;
    int w = cell - h * Wd;
    const float* db = deltas + (size_t)(4 * a) * HW + cell;
    float dx = db[0];
    float dy = db[HW];
    float dw = db[2 * HW];
    float dh = db[3 * HW];
    dw = fminf(fmaxf(dw, -10.f), 10.f);
    dh = fminf(fmaxf(dh, -10.f), 10.f);

    float ww = c_aw[a], hh = c_ah[a];
    float cx = 16.f * (float)w + 8.f;   // exact
    float cy = 16.f * (float)h + 8.f;   // exact

    float pcx = __fadd_rn(__fmul_rn(dx, ww), cx);
    float pcy = __fadd_rn(__fmul_rn(dy, hh), cy);
    float pw  = __fmul_rn(expf(dw), ww);
    float ph  = __fmul_rn(expf(dh), hh);
    float hpw = __fmul_rn(0.5f, pw);
    float hph = __fmul_rn(0.5f, ph);
    float x1 = __fsub_rn(pcx, hpw);
    float x2 = __fadd_rn(pcx, hpw);
    float y1 = __fsub_rn(pcy, hph);
    float y2 = __fadd_rn(pcy, hph);

    float xmax = __fsub_rn(info1, 1.f);
    float ymax = __fsub_rn(info0, 1.f);
    x1 = fminf(fmaxf(x1, 0.f), xmax);
    x2 = fminf(fmaxf(x2, 0.f), xmax);
    y1 = fminf(fmaxf(y1, 0.f), ymax);
    y2 = fminf(fmaxf(y2, 0.f), ymax);

    float msz = __fmul_rn(16.f, info2);
    *valid = (__fadd_rn(__fsub_rn(x2, x1), 1.f) >= msz) &&
             (__fadd_rn(__fsub_rn(y2, y1), 1.f) >= msz);
    return make_float4(x1, y1, x2, y2);
}

// ---------------- init: zero hist32k (128 KB) + dup_state ----------------
__global__ __launch_bounds__(256) void init_kernel(float4* zH, float4* zS) {
    int t = blockIdx.x * 256 + threadIdx.x;
    float4 z = make_float4(0.f, 0.f, 0.f, 0.f);
    if (t < 8192) zH[t] = z;
    else if (t < 8192 + 16) zS[t - 8192] = z;
}

// decode (r13 form). hist pointer is a parameter so the PROBE duplicate can
// redirect its atomics to a dummy buffer (keys writes are idempotent).
__global__ __launch_bounds__(256) void decode_kernel(const float* __restrict__ scores,
                                                     const float* __restrict__ deltas,
                                                     const float* __restrict__ iminfo,
                                                     unsigned int* __restrict__ keys,
                                                     unsigned int* __restrict__ hist,
                                                     float4* __restrict__ zA,
                                                     float4* __restrict__ zB) {
    __shared__ unsigned int lhp[NBUCK / 2];   // 64 KB: bucket pairs
    for (int i = threadIdx.x; i < NBUCK / 2; i += 256) lhp[i] = 0u;

    int t = blockIdx.x * 256 + threadIdx.x;
    float4 z = make_float4(0.f, 0.f, 0.f, 0.f);
    if (t < 4100) zA[t] = z;
    else if (t < 4148) zB[t - 4100] = z;

    int a = t / HW;
    int cell = t - a * HW;
    float score = scores[(AA + a) * HW + cell];
    bool valid;
    (void)decode_box(a, cell, deltas, iminfo[0], iminfo[1], iminfo[2], &valid);
    unsigned int sb = __float_as_uint(score);
    unsigned int key = valid ? ((sb & 0x80000000u) ? ~sb : (sb | 0x80000000u))
                             : 0x007FFFFFu;
    keys[t] = key;
    __syncthreads();
    unsigned int b = key >> BSHIFT;
    atomicAdd(&lhp[b >> 1], 1u << ((b & 1u) << 4));
    __syncthreads();
    for (int i = threadIdx.x; i < NBUCK / 2; i += 256) {
        unsigned int v = lhp[i];
        if (v) {
            unsigned int lo = v & 0xFFFFu, hi = v >> 16;
            if (lo) atomicAdd(&hist[rot15(2u * i)], lo);
            if (hi) atomicAdd(&hist[rot15(2u * i + 1u)], hi);
        }
    }
}

// compact (r13 form). state/cand are parameters so the probe duplicate
// writes to dummy buffers (reads the same keys/hist -> same T, same work).
__global__ __launch_bounds__(256) void compact_kernel(const unsigned int* __restrict__ keys,
                                                      const unsigned int* __restrict__ hist,
                                                      unsigned int* __restrict__ state,
                                                      u64* __restrict__ cand) {
    __shared__ unsigned int sfx[256];
    __shared__ unsigned int sC, sGt, sT;
    int t = threadIdx.x;

    unsigned int part = 0;
    int rbase = t * 128;
    for (int j = 0; j < 128; ++j) part += hist[rot15((unsigned int)(rbase + j))];
    sfx[t] = part;
    __syncthreads();
    for (int d = 1; d < 256; d <<= 1) {
        unsigned int v = (t + d < 256) ? sfx[t + d] : 0u;
        __syncthreads();
        sfx[t] += v;
        __syncthreads();
    }
    {
        unsigned int ge = sfx[t];
        unsigned int gt = (t < 255) ? sfx[t + 1] : 0u;
        if (ge >= TOPN && gt < TOPN) { sC = (unsigned int)t; sGt = gt; }
    }
    __syncthreads();
    unsigned int cbase = sC * 128u;
    unsigned int gtA = sGt;
    unsigned int e = (t < 128) ? hist[rot15(cbase + (unsigned int)t)] : 0u;
    __syncthreads();
    sfx[t] = e;
    __syncthreads();
    for (int d = 1; d < 256; d <<= 1) {
        unsigned int v = (t + d < 256) ? sfx[t + d] : 0u;
        __syncthreads();
        sfx[t] += v;
        __syncthreads();
    }
    {
        unsigned int ge = sfx[t] + gtA;
        unsigned int gt = ((t < 255) ? sfx[t + 1] : 0u) + gtA;
        if (t < 128 && ge >= TOPN && gt < TOPN)
            sT = (cbase + (unsigned int)t) << BSHIFT;
    }
    __syncthreads();
    unsigned int T = sT;

    int i = blockIdx.x * 256 + t;
    unsigned int k = keys[i];
    if (k >= T) {
        unsigned int pos = atomicAdd(&state[2], 1u);
        if (pos < CAND_CAP) {
            int a = i / HW;
            int cell = i - a * HW;
            unsigned int aidx = (unsigned int)(cell * 9 + a);
            cand[pos] = ((u64)k << 32) | (u64)(~aidx);
        }
    }
}

// fused exact-rank + scatter (idempotent: deterministic same-value writes).
__global__ __launch_bounds__(256) void rank_scatter_kernel(const u64* __restrict__ cand,
                                                           const float* __restrict__ deltas,
                                                           const float* __restrict__ iminfo,
                                                           float4* __restrict__ tb,
                                                           u64* __restrict__ vmask) {
    __shared__ u64 s[CAND_CAP];
    for (int j = threadIdx.x; j < CAND_CAP; j += 256) s[j] = cand[j];
    int part = threadIdx.x & 7;
    int i = blockIdx.x * 32 + (threadIdx.x >> 3);
    u64 k = cand[i];
    __syncthreads();
    const ulonglong2* sv = (const ulonglong2*)s;
    unsigned int cnt = 0;
    #pragma unroll 8
    for (int jj = part; jj < CAND_CAP / 2; jj += 8) {
        ulonglong2 v = sv[jj];
        cnt += (v.x > k) ? 1u : 0u;
        cnt += (v.y > k) ? 1u : 0u;
    }
    cnt += __shfl_xor(cnt, 1);
    cnt += __shfl_xor(cnt, 2);
    cnt += __shfl_xor(cnt, 4);
    if (part == 0 && k != 0ull && cnt < TOPN) {
        unsigned int aidx = ~((unsigned int)k);
        int a = (int)(aidx % 9u);
        int cell = (int)(aidx / 9u);
        bool valid;
        float4 box = decode_box(a, cell, deltas, iminfo[0], iminfo[1], iminfo[2], &valid);
        tb[cnt] = box;
        if ((unsigned int)(k >> 32) != 0x007FFFFFu)
            atomicOr(&vmask[cnt >> 6], 1ull << (cnt & 63));
    }
}

// suppression bit-matrix, upper-triangle word-blocks only (pure -> idempotent).
__global__ __launch_bounds__(64) void nms_matrix_kernel(const float4* __restrict__ tb,
                                                        u64* __restrict__ mat) {
    if (blockIdx.x < blockIdx.y) return;
    __shared__ float4 cb[64];
    int t = threadIdx.x;
    int c0 = blockIdx.x * 64;
    int col = c0 + t;
    cb[t] = (col < TOPN) ? tb[col] : make_float4(0.f, 0.f, 0.f, 0.f);
    __syncthreads();
    int row = blockIdx.y * 64 + t;
    if (row >= TOPN) return;
    float4 rb = tb[row];
    float rA = (rb.z - rb.x) * (rb.w - rb.y);
    u64 mask = 0ull;
    for (int c = 0; c < 64; ++c) {
        if (c0 + c >= TOPN) break;
        float4 b = cb[c];
        float lx = fmaxf(rb.x, b.x), ly = fmaxf(rb.y, b.y);
        float rx = fminf(rb.z, b.z), ry = fminf(rb.w, b.w);
        float iw = fmaxf(rx - lx, 0.f), ih = fmaxf(ry - ly, 0.f);
        float inter = iw * ih;
        float bA = (b.z - b.x) * (b.w - b.y);
        float iou = inter / ((rA + bA) - inter);
        if (iou > 0.7f) mask |= (1ull << c);   // NaN compares false, as in numpy
    }
    mat[(size_t)row * NWORDS + blockIdx.x] = mask;
}

// 64-bit readlane with wave-uniform index.
__device__ __forceinline__ u64 rdl64(u64 v, int l) {
    unsigned int lo = (unsigned int)__builtin_amdgcn_readlane((int)(unsigned int)v, l);
    unsigned int hi = (unsigned int)__builtin_amdgcn_readlane((int)(unsigned int)(v >> 32), l);
    return ((u64)hi << 32) | (u64)lo;
}

// single-wave greedy scan — ROUND-0 structure, verbatim (67 µs anchor).
__global__ __launch_bounds__(64) void nms_scan_kernel(const u64* __restrict__ mat,
                                                      const u64* __restrict__ vmask,
                                                      const float4* __restrict__ tb,
                                                      float* __restrict__ out) {
    int lane = threadIdx.x;
    u64 r0 = ~vmask[lane];
    u64 r1 = (lane < NWORDS - 64) ? ~vmask[64 + lane] : ~0ull;
    __shared__ int kept[POSTN];
    int cnt = 0;

    u64 a0, a1, b0, b1;
    {
        ulonglong2 vA = *(const ulonglong2*)(mat + (size_t)lane * NWORDS);
        ulonglong2 vB = *(const ulonglong2*)(mat + (size_t)(64 + lane) * NWORDS);
        a0 = vA.x; a1 = vA.y; b0 = vB.x; b1 = vB.y;
    }
    for (int c = 0; c < NCHUNK; ++c) {
        u64 na0 = 0, na1 = 0, nb0 = 0, nb1 = 0;
        if (c + 1 < NCHUNK) {
            const u64* pA = mat + (size_t)((c + 1) * 128 + lane) * NWORDS + 2 * (c + 1);
            const u64* pB = mat + (size_t)((c + 1) * 128 + 64 + lane) * NWORDS + 2 * (c + 1);
            ulonglong2 vA = *(const ulonglong2*)pA;
            ulonglong2 vB = *(const ulonglong2*)pB;
            na0 = vA.x; na1 = vA.y; nb0 = vB.x; nb1 = vB.y;
        }
        int w2 = 2 * c;
        u64 s0 = (w2 < 64) ? rdl64(r0, w2) : rdl64(r1, w2 - 64);
        u64 s1 = (w2 + 1 < 64) ? rdl64(r0, w2 + 1) : rdl64(r1, w2 + 1 - 64);
        if ((s0 & s1) != ~0ull) {
            int base = c * 128;
            u64 rem0 = s0, rem1 = s1, k0 = 0ull, k1 = 0ull;
            while (cnt < POSTN) {
                int b;
                if (~rem0) b = __ffsll((u64)~rem0) - 1;
                else if (~rem1) b = 64 + __ffsll((u64)~rem1) - 1;
                else break;
                if (lane == 0) kept[cnt] = base + b;
                ++cnt;
                u64 w0, w1;
                if (b < 64) {
                    w0 = rdl64(a0, b); w1 = rdl64(a1, b);
                    k0 |= 1ull << b; rem0 |= 1ull << b;
                } else {
                    int bb = b - 64;
                    w0 = rdl64(b0, bb); w1 = rdl64(b1, bb);
                    k1 |= 1ull << bb; rem1 |= 1ull << bb;
                }
                rem0 |= w0; rem1 |= w1;
            }
            if (cnt >= POSTN) break;
            u64 f0 = 0ull, f1 = 0ull, m0 = k0, m1 = k1;
            while (m0 | m1) {
                int idxs[8];
                #pragma unroll
                for (int j = 0; j < 8; ++j) {
                    int b = -1;
                    if (m0) { b = __ffsll(m0) - 1; m0 &= m0 - 1; }
                    else if (m1) { b = 64 + __ffsll(m1) - 1; m1 &= m1 - 1; }
                    idxs[j] = b;
                }
                u64 v0[8], v1[8];
                #pragma unroll
                for (int j = 0; j < 8; ++j) {
                    v0[j] = 0ull; v1[j] = 0ull;
                    if (idxs[j] >= 0) {
                        const u64* row = mat + (size_t)(base + idxs[j]) * NWORDS;
                        v0[j] = row[lane];
                        if (lane < NWORDS - 64) v1[j] = row[64 + lane];
                    }
                }
                #pragma unroll
                for (int j = 0; j < 8; ++j) { f0 |= v0[j]; f1 |= v1[j]; }
            }
            r0 |= f0; r1 |= f1;
        }
        a0 = na0; a1 = na1; b0 = nb0; b1 = nb1;
    }

    for (int r = lane; r < POSTN; r += 64) {
        float4 b = make_float4(0.f, 0.f, 0.f, 0.f);
        if (r < cnt) b = tb[kept[r]];
        float* o = out + r * 5;
        o[0] = 0.f; o[1] = b.x; o[2] = b.y; o[3] = b.z; o[4] = b.w;
    }
}

// ---------------- host launcher (MEASUREMENT PROBE) ----------------
// Every non-scan kernel is launched TWICE, each duplicate side-effect-safe
// (idempotent or redirected to scratch). With Delta = new_total - 240.5:
//   Delta = (init + decode + compact + rank + matrix) + 5*gap
//   fixed_base = 240.5 - Delta - 67(scan)
// This decides whether the ~173 us non-scan mass is kernels/gaps or fixed
// overhead. Output is bit-identical to round 13.
extern "C" void kernel_launch(void* const* d_in, const int* in_sizes, int n_in,
                              void* d_out, int out_size, void* d_ws, size_t ws_size,
                              hipStream_t stream) {
    const float* scores = (const float*)d_in[0];
    const float* deltas = (const float*)d_in[1];
    const float* iminfo = (const float*)d_in[2];
    float* out = (float*)d_out;

    char* ws = (char*)d_ws;
    unsigned int* keys    = (unsigned int*)(ws + 0);          // 221184*4  = 884736
    unsigned int* state   = (unsigned int*)(ws + 885760);     // 64
    u64*          cand    = (u64*)(ws + 885824);              // 8192*8    = 65536
    float4*       tb      = (float4*)(ws + 951360);           // 6016*16   = 96256
    u64*          vmask   = (u64*)(ws + 1047616);             // 768
    u64*          mat     = (u64*)(ws + 1048384);             // 6016*94*8 = 4524032
    unsigned int* hist32k = (unsigned int*)(ws + 1048384);    // 32768*4 = 131072 (mat head)
    // probe scratch — inside mat region, beyond hist32k; all dead before
    // nms_matrix writes mat:
    unsigned int* dup_hist  = (unsigned int*)(ws + 1048384 + 131072);  // 128 KB
    unsigned int* dup_state = (unsigned int*)(ws + 1048384 + 262144);  // 256 B
    u64*          dup_cand  = (u64*)(ws + 1048384 + 262400);           // 64 KB

    const int NB = N_ANCH / 256;   // 864 exactly

    // real + duplicate pairs (duplicates immediately after originals)
    init_kernel<<<33, 256, 0, stream>>>((float4*)hist32k, (float4*)dup_state);
    init_kernel<<<33, 256, 0, stream>>>((float4*)hist32k, (float4*)dup_state);

    decode_kernel<<<NB, 256, 0, stream>>>(scores, deltas, iminfo, keys, hist32k,
                                          (float4*)(ws + 885760), (float4*)vmask);
    decode_kernel<<<NB, 256, 0, stream>>>(scores, deltas, iminfo, keys, dup_hist,
                                          (float4*)(ws + 885760), (float4*)vmask);

    compact_kernel<<<NB, 256, 0, stream>>>(keys, hist32k, state, cand);
    compact_kernel<<<NB, 256, 0, stream>>>(keys, hist32k, dup_state, dup_cand);

    rank_scatter_kernel<<<CAND_CAP / 32, 256, 0, stream>>>(cand, deltas, iminfo, tb, vmask);
    rank_scatter_kernel<<<CAND_CAP / 32, 256, 0, stream>>>(cand, deltas, iminfo, tb, vmask);

    nms_matrix_kernel<<<dim3(NWORDS, NWORDS), 64, 0, stream>>>(tb, mat);
    nms_matrix_kernel<<<dim3(NWORDS, NWORDS), 64, 0, stream>>>(tb, mat);

    nms_scan_kernel<<<1, 64, 0, stream>>>(mat, vmask, tb, out);
}

// Round 16
// 241.020 us; speedup vs baseline: 1.4593x; 1.4593x over previous
//
#include <hip/hip_runtime.h>

// ---------------- problem constants ----------------
#define N_ANCH 221184      // H*W*A = 128*192*9
#define HW     24576       // H*W
#define Wd     192
#define AA     9
#define TOPN   6000
#define POSTN  300
#define CAND_CAP 8192
#define NWORDS 94          // ceil(6016/64) words of suppression bits
#define NCHUNK 47          // 6016 / 128
#define NBUCK  32768       // 15-bit select buckets
#define BSHIFT 17          // key >> BSHIFT = bucket

typedef unsigned long long u64;

// anchor widths/heights (== ws2/hs2 of the reference, exact small ints)
__device__ const float c_aw[9] = {184.f,368.f,736.f,128.f,256.f,512.f, 88.f,176.f,352.f};
__device__ const float c_ah[9] = { 96.f,192.f,384.f,128.f,256.f,512.f,176.f,352.f,704.f};

// bucket -> storage permutation. Requirements (r9 + r15 lessons):
//  (a) value-adjacent hot buckets scatter across cache lines (decode flush)
//  (b) level-1 range sums (128 consecutive buckets) read COALESCED (compact)
// s = ((b&0x7F)<<8) | (b>>7): adjacent b -> s 1KB apart (a ✓);
// storage-coalesced word iter*256+t holds bucket t*128+iter, so thread t
// summing over iter gets range t with fully-coalesced reads (b ✓).
__device__ __forceinline__ unsigned int s15(unsigned int b) {
    return ((b & 0x7Fu) << 8) | (b >> 7);
}

// shared box decode — used by decode_kernel AND rank_scatter so the FP
// sequence (and thus every bit of the box) is identical in both places.
__device__ __forceinline__ float4 decode_box(int a, int cell,
                                             const float* __restrict__ deltas,
                                             float info0, float info1, float info2,
                                             bool* valid) {
    int h = cell / Wd;
    int w = cell - h * Wd;
    const float* db = deltas + (size_t)(4 * a) * HW + cell;
    float dx = db[0];
    float dy = db[HW];
    float dw = db[2 * HW];
    float dh = db[3 * HW];
    dw = fminf(fmaxf(dw, -10.f), 10.f);
    dh = fminf(fmaxf(dh, -10.f), 10.f);

    float ww = c_aw[a], hh = c_ah[a];
    float cx = 16.f * (float)w + 8.f;   // exact
    float cy = 16.f * (float)h + 8.f;   // exact

    float pcx = __fadd_rn(__fmul_rn(dx, ww), cx);
    float pcy = __fadd_rn(__fmul_rn(dy, hh), cy);
    float pw  = __fmul_rn(expf(dw), ww);
    float ph  = __fmul_rn(expf(dh), hh);
    float hpw = __fmul_rn(0.5f, pw);
    float hph = __fmul_rn(0.5f, ph);
    float x1 = __fsub_rn(pcx, hpw);
    float x2 = __fadd_rn(pcx, hpw);
    float y1 = __fsub_rn(pcy, hph);
    float y2 = __fadd_rn(pcy, hph);

    float xmax = __fsub_rn(info1, 1.f);
    float ymax = __fsub_rn(info0, 1.f);
    x1 = fminf(fmaxf(x1, 0.f), xmax);
    x2 = fminf(fmaxf(x2, 0.f), xmax);
    y1 = fminf(fmaxf(y1, 0.f), ymax);
    y2 = fminf(fmaxf(y2, 0.f), ymax);

    float msz = __fmul_rn(16.f, info2);
    *valid = (__fadd_rn(__fsub_rn(x2, x1), 1.f) >= msz) &&
             (__fadd_rn(__fsub_rn(y2, y1), 1.f) >= msz);
    return make_float4(x1, y1, x2, y2);
}

// ---------------- init: zero hist32k (128 KB) ----------------
__global__ __launch_bounds__(256) void init_kernel(float4* zH) {
    int t = blockIdx.x * 256 + threadIdx.x;
    zH[t] = make_float4(0.f, 0.f, 0.f, 0.f);   // grid exactly 8192 f4
}

// decode (r13 form, s15 storage). Zeroes state+cand (zA) and vmask (zB).
__global__ __launch_bounds__(256) void decode_kernel(const float* __restrict__ scores,
                                                     const float* __restrict__ deltas,
                                                     const float* __restrict__ iminfo,
                                                     unsigned int* __restrict__ keys,
                                                     unsigned int* __restrict__ hist,
                                                     float4* __restrict__ zA,
                                                     float4* __restrict__ zB) {
    __shared__ unsigned int lhp[NBUCK / 2];   // 64 KB: bucket pairs
    for (int i = threadIdx.x; i < NBUCK / 2; i += 256) lhp[i] = 0u;

    int t = blockIdx.x * 256 + threadIdx.x;
    float4 z = make_float4(0.f, 0.f, 0.f, 0.f);
    if (t < 4100) zA[t] = z;
    else if (t < 4148) zB[t - 4100] = z;

    int a = t / HW;
    int cell = t - a * HW;
    float score = scores[(AA + a) * HW + cell];
    bool valid;
    (void)decode_box(a, cell, deltas, iminfo[0], iminfo[1], iminfo[2], &valid);
    unsigned int sb = __float_as_uint(score);
    // flip to ordered-uint; invalid -> key of -inf (0x007FFFFF)
    unsigned int key = valid ? ((sb & 0x80000000u) ? ~sb : (sb | 0x80000000u))
                             : 0x007FFFFFu;
    keys[t] = key;
    __syncthreads();
    unsigned int b = key >> BSHIFT;
    atomicAdd(&lhp[b >> 1], 1u << ((b & 1u) << 4));
    __syncthreads();
    for (int i = threadIdx.x; i < NBUCK / 2; i += 256) {
        unsigned int v = lhp[i];
        if (v) {
            unsigned int lo = v & 0xFFFFu, hi = v >> 16;
            if (lo) atomicAdd(&hist[s15(2u * i)], lo);
            if (hi) atomicAdd(&hist[s15(2u * i + 1u)], hi);
        }
    }
}

// compact: per-block T recompute, now with COALESCED level-1 (the r13 form's
// 28M scattered reads were the suspected ~30-50 us — r15 probe). Then append
// all keys >= T (boundary bucket fully included; ~6000+<=1728 < CAND_CAP).
__global__ __launch_bounds__(256) void compact_kernel(const unsigned int* __restrict__ keys,
                                                      const unsigned int* __restrict__ hist,
                                                      unsigned int* __restrict__ state,
                                                      u64* __restrict__ cand) {
    __shared__ unsigned int sfx[256];
    __shared__ unsigned int sC, sGt, sT;
    int t = threadIdx.x;

    // level 1: thread t sums storage words iter*256+t (coalesced) = range t
    unsigned int part = 0;
    for (int iter = 0; iter < 128; ++iter) part += hist[iter * 256 + t];
    sfx[t] = part;
    __syncthreads();
    for (int d = 1; d < 256; d <<= 1) {
        unsigned int v = (t + d < 256) ? sfx[t + d] : 0u;
        __syncthreads();
        sfx[t] += v;
        __syncthreads();
    }
    {
        unsigned int ge = sfx[t];
        unsigned int gt = (t < 255) ? sfx[t + 1] : 0u;
        if (ge >= TOPN && gt < TOPN) { sC = (unsigned int)t; sGt = gt; }
    }
    __syncthreads();
    unsigned int C = sC;
    unsigned int gtA = sGt;
    // level 2: crossing range C's 128 buckets live at storage (t<<8)|C
    unsigned int e = (t < 128) ? hist[((unsigned int)t << 8) | C] : 0u;
    __syncthreads();
    sfx[t] = e;
    __syncthreads();
    for (int d = 1; d < 256; d <<= 1) {
        unsigned int v = (t + d < 256) ? sfx[t + d] : 0u;
        __syncthreads();
        sfx[t] += v;
        __syncthreads();
    }
    {
        unsigned int ge = sfx[t] + gtA;
        unsigned int gt = ((t < 255) ? sfx[t + 1] : 0u) + gtA;
        if (t < 128 && ge >= TOPN && gt < TOPN)
            sT = (C * 128u + (unsigned int)t) << BSHIFT;
    }
    __syncthreads();
    unsigned int T = sT;

    int i = blockIdx.x * 256 + t;
    unsigned int k = keys[i];
    if (k >= T) {
        unsigned int pos = atomicAdd(&state[2], 1u);
        if (pos < CAND_CAP) {
            int a = i / HW;
            int cell = i - a * HW;
            unsigned int aidx = (unsigned int)(cell * 9 + a);  // reference anchor index
            cand[pos] = ((u64)k << 32) | (u64)(~aidx);
        }
    }
}

// fused exact-rank + scatter (unchanged, proven).
__global__ __launch_bounds__(256) void rank_scatter_kernel(const u64* __restrict__ cand,
                                                           const float* __restrict__ deltas,
                                                           const float* __restrict__ iminfo,
                                                           float4* __restrict__ tb,
                                                           u64* __restrict__ vmask) {
    __shared__ u64 s[CAND_CAP];
    for (int j = threadIdx.x; j < CAND_CAP; j += 256) s[j] = cand[j];
    int part = threadIdx.x & 7;
    int i = blockIdx.x * 32 + (threadIdx.x >> 3);
    u64 k = cand[i];
    __syncthreads();
    const ulonglong2* sv = (const ulonglong2*)s;
    unsigned int cnt = 0;
    #pragma unroll 8
    for (int jj = part; jj < CAND_CAP / 2; jj += 8) {
        ulonglong2 v = sv[jj];
        cnt += (v.x > k) ? 1u : 0u;
        cnt += (v.y > k) ? 1u : 0u;
    }
    cnt += __shfl_xor(cnt, 1);
    cnt += __shfl_xor(cnt, 2);
    cnt += __shfl_xor(cnt, 4);
    if (part == 0 && k != 0ull && cnt < TOPN) {
        unsigned int aidx = ~((unsigned int)k);
        int a = (int)(aidx % 9u);
        int cell = (int)(aidx / 9u);
        bool valid;
        float4 box = decode_box(a, cell, deltas, iminfo[0], iminfo[1], iminfo[2], &valid);
        tb[cnt] = box;
        if ((unsigned int)(k >> 32) != 0x007FFFFFu)
            atomicOr(&vmask[cnt >> 6], 1ull << (cnt & 63));
    }
}

// suppression bit-matrix, upper-triangle word-blocks only. Blocks belonging
// to a chunk's diagonal 128x128 region ALSO write the packed diag array
// diagp[c][128][2] so the scan's per-chunk working set is 16 cache lines
// instead of 128. Sub-diagonal [c][64+r][0] stays unwritten (garbage) —
// harmless, same as the unwritten mat words round 0's scan already reads.
__global__ __launch_bounds__(64) void nms_matrix_kernel(const float4* __restrict__ tb,
                                                        u64* __restrict__ mat,
                                                        u64* __restrict__ diagp) {
    if (blockIdx.x < blockIdx.y) return;
    __shared__ float4 cb[64];
    int t = threadIdx.x;
    int c0 = blockIdx.x * 64;
    int col = c0 + t;
    cb[t] = (col < TOPN) ? tb[col] : make_float4(0.f, 0.f, 0.f, 0.f);
    __syncthreads();
    int row = blockIdx.y * 64 + t;
    if (row >= TOPN) return;
    float4 rb = tb[row];
    float rA = (rb.z - rb.x) * (rb.w - rb.y);
    u64 mask = 0ull;
    for (int c = 0; c < 64; ++c) {
        if (c0 + c >= TOPN) break;
        float4 b = cb[c];
        float lx = fmaxf(rb.x, b.x), ly = fmaxf(rb.y, b.y);
        float rx = fminf(rb.z, b.z), ry = fminf(rb.w, b.w);
        float iw = fmaxf(rx - lx, 0.f), ih = fmaxf(ry - ly, 0.f);
        float inter = iw * ih;
        float bA = (b.z - b.x) * (b.w - b.y);
        float iou = inter / ((rA + bA) - inter);
        if (iou > 0.7f) mask |= (1ull << c);   // NaN compares false, as in numpy
    }
    mat[(size_t)row * NWORDS + blockIdx.x] = mask;
    if ((blockIdx.x >> 1) == (blockIdx.y >> 1)) {
        int c = blockIdx.x >> 1;
        int rin = ((blockIdx.y & 1) << 6) + t;
        diagp[((size_t)c * 128 + rin) * 2 + (blockIdx.x & 1)] = mask;
    }
}

// 64-bit readlane with wave-uniform index.
__device__ __forceinline__ u64 rdl64(u64 v, int l) {
    unsigned int lo = (unsigned int)__builtin_amdgcn_readlane((int)(unsigned int)v, l);
    unsigned int hi = (unsigned int)__builtin_amdgcn_readlane((int)(unsigned int)(v >> 32), l);
    return ((u64)hi << 32) | (u64)lo;
}

// single-wave greedy scan — ROUND-0 structure; diag reads now come from the
// PACKED diagp (coalesced, 4x fewer lines). Propagation rows still from mat.
__global__ __launch_bounds__(64) void nms_scan_kernel(const u64* __restrict__ mat,
                                                      const u64* __restrict__ diagp,
                                                      const u64* __restrict__ vmask,
                                                      const float4* __restrict__ tb,
                                                      float* __restrict__ out) {
    int lane = threadIdx.x;
    u64 r0 = ~vmask[lane];
    u64 r1 = (lane < NWORDS - 64) ? ~vmask[64 + lane] : ~0ull;
    __shared__ int kept[POSTN];
    int cnt = 0;

    const ulonglong2* dp = (const ulonglong2*)diagp;   // [c*128 + r]
    u64 a0, a1, b0, b1;
    {
        ulonglong2 vA = dp[lane];
        ulonglong2 vB = dp[64 + lane];
        a0 = vA.x; a1 = vA.y; b0 = vB.x; b1 = vB.y;
    }
    for (int c = 0; c < NCHUNK; ++c) {
        u64 na0 = 0, na1 = 0, nb0 = 0, nb1 = 0;
        if (c + 1 < NCHUNK) {
            ulonglong2 vA = dp[(c + 1) * 128 + lane];
            ulonglong2 vB = dp[(c + 1) * 128 + 64 + lane];
            na0 = vA.x; na1 = vA.y; nb0 = vB.x; nb1 = vB.y;
        }
        int w2 = 2 * c;
        u64 s0 = (w2 < 64) ? rdl64(r0, w2) : rdl64(r1, w2 - 64);
        u64 s1 = (w2 + 1 < 64) ? rdl64(r0, w2 + 1) : rdl64(r1, w2 + 1 - 64);
        if ((s0 & s1) != ~0ull) {
            int base = c * 128;
            u64 rem0 = s0, rem1 = s1, k0 = 0ull, k1 = 0ull;
            while (cnt < POSTN) {
                int b;
                if (~rem0) b = __ffsll((u64)~rem0) - 1;
                else if (~rem1) b = 64 + __ffsll((u64)~rem1) - 1;
                else break;
                if (lane == 0) kept[cnt] = base + b;
                ++cnt;
                u64 w0, w1;
                if (b < 64) {
                    w0 = rdl64(a0, b); w1 = rdl64(a1, b);
                    k0 |= 1ull << b; rem0 |= 1ull << b;
                } else {
                    int bb = b - 64;
                    w0 = rdl64(b0, bb); w1 = rdl64(b1, bb);
                    k1 |= 1ull << bb; rem1 |= 1ull << bb;
                }
                rem0 |= w0; rem1 |= w1;
            }
            if (cnt >= POSTN) break;
            u64 f0 = 0ull, f1 = 0ull, m0 = k0, m1 = k1;
            while (m0 | m1) {
                int idxs[8];
                #pragma unroll
                for (int j = 0; j < 8; ++j) {
                    int b = -1;
                    if (m0) { b = __ffsll(m0) - 1; m0 &= m0 - 1; }
                    else if (m1) { b = 64 + __ffsll(m1) - 1; m1 &= m1 - 1; }
                    idxs[j] = b;
                }
                u64 v0[8], v1[8];
                #pragma unroll
                for (int j = 0; j < 8; ++j) {
                    v0[j] = 0ull; v1[j] = 0ull;
                    if (idxs[j] >= 0) {
                        const u64* row = mat + (size_t)(base + idxs[j]) * NWORDS;
                        v0[j] = row[lane];
                        if (lane < NWORDS - 64) v1[j] = row[64 + lane];
                    }
                }
                #pragma unroll
                for (int j = 0; j < 8; ++j) { f0 |= v0[j]; f1 |= v1[j]; }
            }
            r0 |= f0; r1 |= f1;
        }
        a0 = na0; a1 = na1; b0 = nb0; b1 = nb1;
    }

    for (int r = lane; r < POSTN; r += 64) {
        float4 b = make_float4(0.f, 0.f, 0.f, 0.f);
        if (r < cnt) b = tb[kept[r]];
        float* o = out + r * 5;
        o[0] = 0.f; o[1] = b.x; o[2] = b.y; o[3] = b.z; o[4] = b.w;
    }
}

// ---------------- host launcher ----------------
extern "C" void kernel_launch(void* const* d_in, const int* in_sizes, int n_in,
                              void* d_out, int out_size, void* d_ws, size_t ws_size,
                              hipStream_t stream) {
    const float* scores = (const float*)d_in[0];
    const float* deltas = (const float*)d_in[1];
    const float* iminfo = (const float*)d_in[2];
    float* out = (float*)d_out;

    char* ws = (char*)d_ws;
    // workspace layout (16B-aligned), total 5,572,416 bytes
    unsigned int* keys    = (unsigned int*)(ws + 0);          // 221184*4  = 884736
    unsigned int* state   = (unsigned int*)(ws + 885760);     // 64
    u64*          cand    = (u64*)(ws + 885824);              // 8192*8    = 65536
    float4*       tb      = (float4*)(ws + 951360);           // 6016*16   = 96256
    u64*          vmask   = (u64*)(ws + 1047616);             // 768
    u64*          mat     = (u64*)(ws + 1048384);             // 6016*94*8 = 4524032
    // hist32k reuses mat's first 128 KB (last read: compact, before matrix).
    unsigned int* hist32k = (unsigned int*)(ws + 1048384);    // 131072
    // diagp reuses the keys region head (keys last read: compact; diagp
    // written by matrix, read by scan). 47*128*2*8 = 96256 B.
    u64*          diagp   = (u64*)(ws + 0);

    const int NB = N_ANCH / 256;   // 864 exactly

    init_kernel<<<32, 256, 0, stream>>>((float4*)hist32k);
    decode_kernel<<<NB, 256, 0, stream>>>(scores, deltas, iminfo, keys, hist32k,
                                          (float4*)(ws + 885760), (float4*)vmask);
    compact_kernel<<<NB, 256, 0, stream>>>(keys, hist32k, state, cand);
    rank_scatter_kernel<<<CAND_CAP / 32, 256, 0, stream>>>(cand, deltas, iminfo, tb, vmask);
    nms_matrix_kernel<<<dim3(NWORDS, NWORDS), 64, 0, stream>>>(tb, mat, diagp);
    nms_scan_kernel<<<1, 64, 0, stream>>>(mat, diagp, vmask, tb, out);
}